// Round 15
// baseline (430.945 us; speedup 1.0000x reference)
//
#include <hip/hip_runtime.h>

#define NN 50000
#define NE 800000
#define NCHUNK 196  // ceil(NN/256)

typedef __attribute__((ext_vector_type(4))) float f32x4;
typedef __attribute__((ext_vector_type(8))) short bf16x8;
typedef __attribute__((ext_vector_type(4))) short bf16x4;

// bf16 round-to-nearest-even helpers
__device__ __forceinline__ short f2bf(float x) {
    unsigned u = __float_as_uint(x);
    unsigned r = (u + 0x7fffu + ((u >> 16) & 1u)) >> 16;
    return (short)r;
}
__device__ __forceinline__ float bf2f(short s) {
    return __uint_as_float(((unsigned)(unsigned short)s) << 16);
}

// ================= CSR build =================

__global__ void deg_count_kernel(const int* __restrict__ dst, int* __restrict__ counts) {
    int e = blockIdx.x * 256 + threadIdx.x;
    if (e < NE) atomicAdd(&counts[dst[e]], 1);
}

__global__ void chunk_sum_kernel(const int* __restrict__ counts, int* __restrict__ partials) {
    int i = blockIdx.x * 256 + threadIdx.x;
    int v = (i < NN) ? counts[i] : 0;
    for (int o = 32; o; o >>= 1) v += __shfl_down(v, o);
    __shared__ int red[4];
    if ((threadIdx.x & 63) == 0) red[threadIdx.x >> 6] = v;
    __syncthreads();
    if (threadIdx.x == 0) partials[blockIdx.x] = red[0] + red[1] + red[2] + red[3];
}

__global__ void scan_partials_kernel(const int* __restrict__ partials, int* __restrict__ chunk_off) {
    __shared__ int s[256];
    int t = threadIdx.x;
    int v = (t < NCHUNK) ? partials[t] : 0;
    s[t] = v;
    __syncthreads();
    for (int o = 1; o < 256; o <<= 1) {
        int u = (t >= o) ? s[t - o] : 0;
        __syncthreads();
        s[t] += u;
        __syncthreads();
    }
    chunk_off[t] = s[t] - v;  // exclusive
}

__global__ void scan_chunks_kernel(const int* __restrict__ counts, const int* __restrict__ chunk_off,
                                   int* __restrict__ row_ptr, int* __restrict__ cursor,
                                   float* __restrict__ dinv) {
    __shared__ int s[256];
    int b = blockIdx.x, t = threadIdx.x;
    int i = b * 256 + t;
    int c = (i < NN) ? counts[i] : 0;
    s[t] = c;
    __syncthreads();
    for (int o = 1; o < 256; o <<= 1) {
        int u = (t >= o) ? s[t - o] : 0;
        __syncthreads();
        s[t] += u;
        __syncthreads();
    }
    if (i < NN) {
        int start = chunk_off[b] + s[t] - c;  // exclusive prefix
        row_ptr[i] = start;
        cursor[i]  = start;
        dinv[i] = rsqrtf((float)(c + 1));  // +1 self loop
    }
}

// packed edge: {src, norm_bits} -- one 8B random store here, one 8B stream read in aggregate
__global__ void fill_csr_kernel(const int* __restrict__ src, const int* __restrict__ dst,
                                const float* __restrict__ dinv, int* __restrict__ cursor,
                                int2* __restrict__ edges) {
    int e = blockIdx.x * 256 + threadIdx.x;
    if (e >= NE) return;
    int s_ = src[e], d = dst[e];
    int p = atomicAdd(&cursor[d], 1);
    edges[p] = make_int2(s_, __float_as_int(dinv[s_] * dinv[d]));
}

// ================= W pre-pass: transpose + split to bf16 hi/lo =================
// in:  W [K=256][N=256] row-major fp32 ; out: Wh/Wl [N][K] bf16 bits

__global__ void wconv_kernel(const float* __restrict__ W, short* __restrict__ Wh,
                             short* __restrict__ Wl) {
    int idx = blockIdx.x * 256 + threadIdx.x;  // 65536
    int k = idx >> 8, n = idx & 255;
    float x = W[idx];
    short h = f2bf(x);
    short l = f2bf(x - bf2f(h));
    Wh[n * 256 + k] = h;
    Wl[n * 256 + k] = l;
}

// ================= split-bf16 MFMA GEMM: C_bf16[M,256] = act(A[M,256]) @ W =================
// A fp32 -> hi/lo bf16 split during LDS staging; W pre-split/pre-transposed.
// C stored bf16 (halves the gather-bound aggregate's traffic -- measured lever).
// hi*hi + hi*lo + lo*hi (lo*lo dropped) -> ~fp32 mantissa.
// act = relu(a + bias[k]) when RELU_BIAS (fuses layer-1 bias+relu into GEMM2's A-load).

#define BM 64
#define BK 32
#define PK 40  // padded k-stride in LDS (80B rows -> 2-way banks, free)

template <bool RELU_BIAS>
__global__ __launch_bounds__(256) void mgemm_kernel(const float* __restrict__ A,
                                                    const short* __restrict__ Wh,
                                                    const short* __restrict__ Wl,
                                                    const float* __restrict__ bias,
                                                    short* __restrict__ C, int M) {
    __shared__ __align__(16) short Ah[BM * PK], Al[BM * PK];
    __shared__ __align__(16) short Bh[256 * PK], Bl[256 * PK];
    const int tid  = threadIdx.x;
    const int lane = tid & 63;
    const int wave = tid >> 6;
    const int row0 = blockIdx.x * BM;
    const int wcol = wave * 64;   // this wave's 64-col slice of N=256

    const int l15 = lane & 15;
    const int kb  = (lane >> 4) * 8;   // k-block of this lane within frag

    const int arow  = tid >> 2;        // 0..63   A staging row
    const int akoff = (tid & 3) * 8;   // 0,8,16,24

    f32x4 acc[4][4] = {};  // [mf][nf] 16x16 frags -> 64x64 per wave

    for (int k0 = 0; k0 < 256; k0 += BK) {
        // ---- load + convert A slice ----
        float xv[8];
        int grow = row0 + arow;
        if (grow < M) {
            float4 a0 = *(const float4*)&A[(size_t)grow * 256 + k0 + akoff];
            float4 a1 = *(const float4*)&A[(size_t)grow * 256 + k0 + akoff + 4];
            xv[0] = a0.x; xv[1] = a0.y; xv[2] = a0.z; xv[3] = a0.w;
            xv[4] = a1.x; xv[5] = a1.y; xv[6] = a1.z; xv[7] = a1.w;
        } else {
#pragma unroll
            for (int i = 0; i < 8; ++i) xv[i] = 0.f;
        }
        if (RELU_BIAS) {
#pragma unroll
            for (int i = 0; i < 8; ++i) xv[i] = fmaxf(xv[i] + bias[k0 + akoff + i], 0.f);
        }
        bf16x8 hv, lv;
#pragma unroll
        for (int i = 0; i < 8; ++i) {
            short h = f2bf(xv[i]);
            hv[i] = h;
            lv[i] = f2bf(xv[i] - bf2f(h));
        }

        __syncthreads();  // previous iter's frag reads done before overwrite
        *(bf16x8*)&Ah[arow * PK + akoff] = hv;
        *(bf16x8*)&Al[arow * PK + akoff] = lv;

        // ---- stage B slice: thread t owns row n=t (vector loads, pre-split W) ----
        {
            const short* sh = &Wh[tid * 256 + k0];
            const short* sl = &Wl[tid * 256 + k0];
#pragma unroll
            for (int c = 0; c < 4; ++c) {
                *(bf16x8*)&Bh[tid * PK + c * 8] = *(const bf16x8*)&sh[c * 8];
                *(bf16x8*)&Bl[tid * PK + c * 8] = *(const bf16x8*)&sl[c * 8];
            }
        }
        __syncthreads();

        // ---- MFMA: 16 frag-pairs x 3 products ----
        bf16x8 bh[4], bl[4];
#pragma unroll
        for (int nf = 0; nf < 4; ++nf) {
            int col = wcol + nf * 16 + l15;
            bh[nf] = *(const bf16x8*)&Bh[col * PK + kb];
            bl[nf] = *(const bf16x8*)&Bl[col * PK + kb];
        }
#pragma unroll
        for (int mf = 0; mf < 4; ++mf) {
            int r = mf * 16 + l15;
            bf16x8 ah = *(const bf16x8*)&Ah[r * PK + kb];
            bf16x8 al = *(const bf16x8*)&Al[r * PK + kb];
#pragma unroll
            for (int nf = 0; nf < 4; ++nf) {
                acc[mf][nf] = __builtin_amdgcn_mfma_f32_16x16x32_bf16(ah, bh[nf], acc[mf][nf], 0, 0, 0);
                acc[mf][nf] = __builtin_amdgcn_mfma_f32_16x16x32_bf16(ah, bl[nf], acc[mf][nf], 0, 0, 0);
                acc[mf][nf] = __builtin_amdgcn_mfma_f32_16x16x32_bf16(al, bh[nf], acc[mf][nf], 0, 0, 0);
            }
        }
    }

    // ---- store bf16: D row = 4*(lane>>4)+r, col = lane&15 ----
    const int orow = 4 * (lane >> 4);
#pragma unroll
    for (int mf = 0; mf < 4; ++mf) {
#pragma unroll
        for (int r = 0; r < 4; ++r) {
            int grow = row0 + mf * 16 + orow + r;
            if (grow < M) {
#pragma unroll
                for (int nf = 0; nf < 4; ++nf) {
                    C[(size_t)grow * 256 + wcol + nf * 16 + l15] = f2bf(acc[mf][nf][r]);
                }
            }
        }
    }
}

// ================= CSR aggregation: channel-split (2 sequential passes) =================
// agg[d, P*128 : P*128+128] = xw[d,slice]*dinv[d]^2 + sum_e xw[src_e,slice]*nrm_e
// Pass working set = 12.8 MB (vs 25.6 full-row), doubling the fraction each 4MB
// per-XCD L2 can hold -> higher hit rate on the ~3.9 TB/s L2-fill-limited gather.
// Passes are SEQUENTIAL dispatches (not grid-z) so they don't interleave.
// Per-channel accumulation order unchanged -> bitwise-identical numerics.

template <int PASS>
__global__ __launch_bounds__(256) void aggregate_kernel(const short* __restrict__ xw,
                                                        const int* __restrict__ row_ptr,
                                                        const int* __restrict__ counts,
                                                        const int2* __restrict__ edges,
                                                        const float* __restrict__ dinv,
                                                        float* __restrict__ agg) {
    int d = blockIdx.x * 8 + (threadIdx.x >> 5);  // 8 half-waves per block
    if (d >= NN) return;
    int lane = threadIdx.x & 31;
    const size_t coff = (size_t)(PASS * 128 + lane * 4);  // this lane's 4-ch slice

    float di = dinv[d];
    float s2 = di * di;
    bf16x4 sv = *(const bf16x4*)&xw[(size_t)d * 256 + coff];
    float acc[4];
#pragma unroll
    for (int i = 0; i < 4; ++i) acc[i] = bf2f(sv[i]) * s2;

    int j = row_ptr[d];
    int end = j + counts[d];

    for (; j + 4 <= end; j += 4) {
        int2 e0 = edges[j + 0], e1 = edges[j + 1], e2 = edges[j + 2], e3 = edges[j + 3];
        bf16x4 v0 = *(const bf16x4*)&xw[(size_t)e0.x * 256 + coff];
        bf16x4 v1 = *(const bf16x4*)&xw[(size_t)e1.x * 256 + coff];
        bf16x4 v2 = *(const bf16x4*)&xw[(size_t)e2.x * 256 + coff];
        bf16x4 v3 = *(const bf16x4*)&xw[(size_t)e3.x * 256 + coff];
        float w0 = __int_as_float(e0.y), w1 = __int_as_float(e1.y);
        float w2 = __int_as_float(e2.y), w3 = __int_as_float(e3.y);
#pragma unroll
        for (int i = 0; i < 4; ++i) acc[i] = fmaf(bf2f(v0[i]), w0, acc[i]);
#pragma unroll
        for (int i = 0; i < 4; ++i) acc[i] = fmaf(bf2f(v1[i]), w1, acc[i]);
#pragma unroll
        for (int i = 0; i < 4; ++i) acc[i] = fmaf(bf2f(v2[i]), w2, acc[i]);
#pragma unroll
        for (int i = 0; i < 4; ++i) acc[i] = fmaf(bf2f(v3[i]), w3, acc[i]);
    }
    for (; j < end; ++j) {
        int2 e = edges[j];
        float w = __int_as_float(e.y);
        bf16x4 v = *(const bf16x4*)&xw[(size_t)e.x * 256 + coff];
#pragma unroll
        for (int i = 0; i < 4; ++i) acc[i] = fmaf(bf2f(v[i]), w, acc[i]);
    }

    *(float4*)&agg[(size_t)d * 256 + coff] = make_float4(acc[0], acc[1], acc[2], acc[3]);
}

// ================= fused epilogue: wave per node =================
// out[i] = (agg2[i,:]+b2) . Wf[0:256] + relu(tf[i,:]@Wt+bt) . Wf[256:512] + bf

__global__ __launch_bounds__(256) void final_kernel(const float* __restrict__ agg2,
                                                    const float* __restrict__ b2,
                                                    const float* __restrict__ tf,
                                                    const float* __restrict__ Wt,
                                                    const float* __restrict__ bt,
                                                    const float* __restrict__ Wf,
                                                    const float* __restrict__ bf,
                                                    float* __restrict__ out) {
    int d = blockIdx.x * 4 + (threadIdx.x >> 6);
    if (d >= NN) return;
    int lane = threadIdx.x & 63;
    int c0 = lane * 4;

    float4 g   = *(const float4*)&agg2[(size_t)d * 256 + c0];
    float4 b2v = *(const float4*)&b2[c0];
    float4 wf0 = *(const float4*)&Wf[c0];
    float4 wf1 = *(const float4*)&Wf[256 + c0];
    float4 wt0 = *(const float4*)&Wt[c0];        // Wt row 0
    float4 wt1 = *(const float4*)&Wt[256 + c0];  // Wt row 1
    float4 btv = *(const float4*)&bt[c0];
    float t0 = tf[d * 2 + 0], t1 = tf[d * 2 + 1];

    float acc = (g.x + b2v.x) * wf0.x + (g.y + b2v.y) * wf0.y +
                (g.z + b2v.z) * wf0.z + (g.w + b2v.w) * wf0.w;
    float xt;
    xt = fmaxf(fmaf(t0, wt0.x, fmaf(t1, wt1.x, btv.x)), 0.f); acc = fmaf(xt, wf1.x, acc);
    xt = fmaxf(fmaf(t0, wt0.y, fmaf(t1, wt1.y, btv.y)), 0.f); acc = fmaf(xt, wf1.y, acc);
    xt = fmaxf(fmaf(t0, wt0.z, fmaf(t1, wt1.z, btv.z)), 0.f); acc = fmaf(xt, wf1.z, acc);
    xt = fmaxf(fmaf(t0, wt0.w, fmaf(t1, wt1.w, btv.w)), 0.f); acc = fmaf(xt, wf1.w, acc);

    acc += __shfl_down(acc, 32);
    acc += __shfl_down(acc, 16);
    acc += __shfl_down(acc, 8);
    acc += __shfl_down(acc, 4);
    acc += __shfl_down(acc, 2);
    acc += __shfl_down(acc, 1);
    if (lane == 0) out[d] = acc + bf[0];
}

// ================= launch =================

extern "C" void kernel_launch(void* const* d_in, const int* in_sizes, int n_in,
                              void* d_out, int out_size, void* d_ws, size_t ws_size,
                              hipStream_t stream) {
    const float* x  = (const float*)d_in[0];
    const int*   ei = (const int*)d_in[1];      // [2, NE] int32
    const float* tf = (const float*)d_in[2];
    const float* W1 = (const float*)d_in[3];
    const float* b1 = (const float*)d_in[4];
    const float* W2 = (const float*)d_in[5];
    const float* b2 = (const float*)d_in[6];
    const float* Wt = (const float*)d_in[7];
    const float* bt = (const float*)d_in[8];
    const float* Wf = (const float*)d_in[9];
    const float* bf = (const float*)d_in[10];
    const int* srcp = ei;
    const int* dstp = ei + NE;

    // workspace layout -- same 110.3 MB proven footprint
    char* ws = (char*)d_ws;
    short* Axw     = (short*)(ws);                       // bf16 xw (25.6MB of 51.2 slot)
    float* B       = (float*)(ws + 51200000);            // fp32 agg1/agg2
    char*  p       = ws + 102400000;
    int*   counts  = (int*)(p);            p += 204800;
    float* dinv    = (float*)(p);          p += 204800;
    int*   row_ptr = (int*)(p);            p += 204800;
    int*   cursor  = (int*)(p);            p += 204800;
    int*   partials= (int*)(p);            p += 4096;
    int*   chunkoff= (int*)(p);            p += 4096;
    int2*  edges   = (int2*)(p);           p += 6400000; // packed {src, nrm}
    short* Wh1     = (short*)(p);          p += 131072;
    short* Wl1     = (short*)(p);          p += 131072;
    short* Wh2     = (short*)(p);          p += 131072;
    short* Wl2     = (short*)(p);          p += 131072;

    // ---- CSR build (d_ws poisoned 0xAA every call -> zero counts first) ----
    hipMemsetAsync(counts, 0, NN * sizeof(int), stream);
    deg_count_kernel<<<(NE + 255) / 256, 256, 0, stream>>>(dstp, counts);
    chunk_sum_kernel<<<NCHUNK, 256, 0, stream>>>(counts, partials);
    scan_partials_kernel<<<1, 256, 0, stream>>>(partials, chunkoff);
    scan_chunks_kernel<<<NCHUNK, 256, 0, stream>>>(counts, chunkoff, row_ptr, cursor, dinv);
    fill_csr_kernel<<<(NE + 255) / 256, 256, 0, stream>>>(srcp, dstp, dinv, cursor, edges);

    // ---- weight split (independent of CSR chain) ----
    wconv_kernel<<<256, 256, 0, stream>>>(W1, Wh1, Wl1);
    wconv_kernel<<<256, 256, 0, stream>>>(W2, Wh2, Wl2);

    int gemm_grid = (NN + BM - 1) / BM;  // 782
    int agg_grid = (NN + 7) / 8;         // 6250 (8 half-waves per block)
    int fin_grid = (NN + 3) / 4;

    // layer 1
    mgemm_kernel<false><<<gemm_grid, 256, 0, stream>>>(x, Wh1, Wl1, nullptr, Axw, NN);
    aggregate_kernel<0><<<agg_grid, 256, 0, stream>>>(Axw, row_ptr, counts, edges, dinv, B);
    aggregate_kernel<1><<<agg_grid, 256, 0, stream>>>(Axw, row_ptr, counts, edges, dinv, B);

    // layer 2 (bias1+relu fused into GEMM A-load)
    mgemm_kernel<true><<<gemm_grid, 256, 0, stream>>>(B, Wh2, Wl2, b1, Axw, NN);
    aggregate_kernel<0><<<agg_grid, 256, 0, stream>>>(Axw, row_ptr, counts, edges, dinv, B);
    aggregate_kernel<1><<<agg_grid, 256, 0, stream>>>(Axw, row_ptr, counts, edges, dinv, B);

    // epilogue
    final_kernel<<<fin_grid, 256, 0, stream>>>(B, b2, tf, Wt, bt, Wf, bf, (float*)d_out);
}